// Round 1
// baseline (373.258 us; speedup 1.0000x reference)
//
#include <hip/hip_runtime.h>
#include <hip/hip_bf16.h>

// Problem constants
#define D_MODEL 256
#define NHEAD 8
#define HEAD_DIM 32
#define KNUM 64            // keys per query
#define LQ 4800
#define NB 2
#define MROWS (NB * LQ)    // 9600
#define LN_EPS 1e-5f

// ---------------------------------------------------------------------------
// Tiled fp32 GEMM: C[M,N] = act(A[M,K] @ W[K,N])
// A may be a virtual concat of A0 (cols < splitK) and A1 (cols >= splitK).
// BM=BN=64, BK=16, 256 threads, 4x4 micro-tile per thread.
// ---------------------------------------------------------------------------
__global__ __launch_bounds__(256) void gemm_f32_kernel(
    const float* __restrict__ A0, int lda0,
    const float* __restrict__ A1, int lda1, int splitK,
    const float* __restrict__ W,
    float* __restrict__ C,
    int M, int N, int K, int do_relu)
{
    __shared__ float As[16][64];   // transposed: As[k][row]
    __shared__ float Ws[16][64];   // Ws[k][col]

    const int t  = threadIdx.x;
    const int tx = t & 15;         // micro-tile col group
    const int ty = t >> 4;         // micro-tile row group
    const int n0 = blockIdx.x * 64;
    const int m0 = blockIdx.y * 64;

    const int arow = t >> 2;       // 0..63  A-tile row this thread stages
    const int ac4  = t & 3;        // 0..3   A-tile float4 col block
    const int wrow = t >> 4;       // 0..15  W-tile row
    const int wc4  = t & 15;       // 0..15  W-tile float4 col block

    float acc[4][4];
#pragma unroll
    for (int i = 0; i < 4; ++i)
#pragma unroll
        for (int j = 0; j < 4; ++j) acc[i][j] = 0.f;

    for (int k0 = 0; k0 < K; k0 += 16) {
        // ---- stage A tile (64 rows x 16 cols), store transposed ----
        const float* Asrc;
        int acol;
        if (splitK && k0 >= splitK) {
            Asrc = A1 + (size_t)(m0 + arow) * lda1;
            acol = (k0 - splitK) + ac4 * 4;
        } else {
            Asrc = A0 + (size_t)(m0 + arow) * lda0;
            acol = k0 + ac4 * 4;
        }
        float4 av = *reinterpret_cast<const float4*>(Asrc + acol);
        // ---- stage W tile (16 rows x 64 cols) ----
        float4 wv = *reinterpret_cast<const float4*>(W + (size_t)(k0 + wrow) * N + n0 + wc4 * 4);

        As[ac4 * 4 + 0][arow] = av.x;
        As[ac4 * 4 + 1][arow] = av.y;
        As[ac4 * 4 + 2][arow] = av.z;
        As[ac4 * 4 + 3][arow] = av.w;
        *reinterpret_cast<float4*>(&Ws[wrow][wc4 * 4]) = wv;
        __syncthreads();

#pragma unroll
        for (int kk = 0; kk < 16; ++kk) {
            float4 a4 = *reinterpret_cast<const float4*>(&As[kk][ty * 4]);
            float4 b4 = *reinterpret_cast<const float4*>(&Ws[kk][tx * 4]);
            float a_[4] = {a4.x, a4.y, a4.z, a4.w};
            float b_[4] = {b4.x, b4.y, b4.z, b4.w};
#pragma unroll
            for (int i = 0; i < 4; ++i)
#pragma unroll
                for (int j = 0; j < 4; ++j)
                    acc[i][j] = fmaf(a_[i], b_[j], acc[i][j]);
        }
        __syncthreads();
    }

#pragma unroll
    for (int i = 0; i < 4; ++i) {
        float4 o;
        o.x = acc[i][0]; o.y = acc[i][1]; o.z = acc[i][2]; o.w = acc[i][3];
        if (do_relu) {
            o.x = fmaxf(o.x, 0.f); o.y = fmaxf(o.y, 0.f);
            o.z = fmaxf(o.z, 0.f); o.w = fmaxf(o.w, 0.f);
        }
        *reinterpret_cast<float4*>(&C[(size_t)(m0 + ty * 4 + i) * N + n0 + tx * 4]) = o;
    }
}

// ---------------------------------------------------------------------------
// Gathered attention: one 256-thread block per query.
// q,k,v: [MROWS, 256] (head-major: h*32+d). idx: [MROWS, 64]. msg out: [MROWS,256].
// ---------------------------------------------------------------------------
__global__ __launch_bounds__(256) void attn_kernel(
    const float* __restrict__ q, const float* __restrict__ k,
    const float* __restrict__ v, const int* __restrict__ idx,
    float* __restrict__ msg)
{
    __shared__ float q_s[256];
    __shared__ float kv_s[32 * 257];   // 32 gathered rows, stride 257 (pad)
    __shared__ float sc_s[8 * 64];     // scores then attn weights
    __shared__ int   idx_s[64];

    const int t  = threadIdx.x;
    const int qi = blockIdx.x;               // 0..9599
    const int n  = qi / LQ;
    const float* kbase = k + (size_t)n * LQ * 256;
    const float* vbase = v + (size_t)n * LQ * 256;

    q_s[t] = q[(size_t)qi * 256 + t];
    if (t < 64) idx_s[t] = idx[(size_t)qi * 64 + t];
    __syncthreads();

    const int h  = t >> 5;   // head 0..7
    const int kl = t & 31;   // key-within-chunk / d index

    // ---- scores ----
    const float scale = 0.17677669529663687f;  // 1/sqrt(32)
    for (int c = 0; c < 2; ++c) {
#pragma unroll 4
        for (int i = 0; i < 32; ++i) {
            int row = idx_s[c * 32 + i];
            kv_s[i * 257 + t] = kbase[(size_t)row * 256 + t];
        }
        __syncthreads();
        float acc = 0.f;
        const float* qs = &q_s[h * 32];
        const float* ks = &kv_s[kl * 257 + h * 32];
#pragma unroll
        for (int d = 0; d < 32; ++d) acc = fmaf(qs[d], ks[d], acc);
        sc_s[h * 64 + c * 32 + kl] = acc * scale;
        __syncthreads();
    }

    // ---- softmax over 64 keys per head (one 32-lane group per head) ----
    {
        float s0 = sc_s[h * 64 + kl];
        float s1 = sc_s[h * 64 + 32 + kl];
        float m = fmaxf(s0, s1);
#pragma unroll
        for (int off = 16; off; off >>= 1) m = fmaxf(m, __shfl_xor(m, off, 32));
        float e0 = expf(s0 - m);
        float e1 = expf(s1 - m);
        float sum = e0 + e1;
#pragma unroll
        for (int off = 16; off; off >>= 1) sum += __shfl_xor(sum, off, 32);
        float inv = 1.f / sum;
        sc_s[h * 64 + kl]      = e0 * inv;
        sc_s[h * 64 + 32 + kl] = e1 * inv;
    }

    // ---- msg = attn @ vg ----
    float macc = 0.f;
    const int d = t & 31;
    for (int c = 0; c < 2; ++c) {
        __syncthreads();   // kv_s reuse + sc_s visibility
#pragma unroll 4
        for (int i = 0; i < 32; ++i) {
            int row = idx_s[c * 32 + i];
            kv_s[i * 257 + t] = vbase[(size_t)row * 256 + t];
        }
        __syncthreads();
#pragma unroll
        for (int i = 0; i < 32; ++i)
            macc = fmaf(sc_s[h * 64 + c * 32 + i], kv_s[i * 257 + h * 32 + d], macc);
    }
    msg[(size_t)qi * 256 + t] = macc;
}

// ---------------------------------------------------------------------------
// LayerNorm over last dim (256). One block per row.
// out = (xadd ? xadd + ln(in)*g+b : ln(in)*g+b)
// ---------------------------------------------------------------------------
__global__ __launch_bounds__(256) void ln_kernel(
    const float* __restrict__ in, const float* __restrict__ g,
    const float* __restrict__ b, const float* __restrict__ xadd,
    float* __restrict__ out)
{
    __shared__ float red[8];
    const int t = threadIdx.x;
    const size_t row = blockIdx.x;
    float val = in[row * 256 + t];

    float s = val;
#pragma unroll
    for (int off = 32; off; off >>= 1) s += __shfl_down(s, off, 64);
    if ((t & 63) == 0) red[t >> 6] = s;
    __syncthreads();
    float mu = (red[0] + red[1] + red[2] + red[3]) * 0.00390625f;

    float dv = val - mu;
    float s2 = dv * dv;
#pragma unroll
    for (int off = 32; off; off >>= 1) s2 += __shfl_down(s2, off, 64);
    if ((t & 63) == 0) red[4 + (t >> 6)] = s2;
    __syncthreads();
    float var = (red[4] + red[5] + red[6] + red[7]) * 0.00390625f;
    float rstd = rsqrtf(var + LN_EPS);

    float r = dv * rstd * g[t] + b[t];
    if (xadd) r += xadd[row * 256 + t];
    out[row * 256 + t] = r;
}

// ---------------------------------------------------------------------------
extern "C" void kernel_launch(void* const* d_in, const int* in_sizes, int n_in,
                              void* d_out, int out_size, void* d_ws, size_t ws_size,
                              hipStream_t stream)
{
    const float* x      = (const float*)d_in[0];
    const float* source = (const float*)d_in[1];
    const int*   eidx   = (const int*)d_in[2];
    const float* Wq     = (const float*)d_in[3];
    const float* Wk     = (const float*)d_in[4];
    const float* Wv     = (const float*)d_in[5];
    const float* Wm     = (const float*)d_in[6];
    const float* W1     = (const float*)d_in[7];
    const float* W2     = (const float*)d_in[8];
    const float* g1     = (const float*)d_in[9];
    const float* b1     = (const float*)d_in[10];
    const float* g2     = (const float*)d_in[11];
    const float* b2     = (const float*)d_in[12];
    float* out = (float*)d_out;

    const size_t SZ = (size_t)MROWS * D_MODEL;   // 2,457,600 floats
    float* wsf = (float*)d_ws;
    float* R0 = wsf;            // q -> msgW -> h2
    float* R1 = wsf + SZ;       // k -> h1 (spans R1+R2)
    float* R2 = wsf + 2 * SZ;   // v
    float* R3 = wsf + 3 * SZ;   // msg -> msgln

    dim3 blk(256);

    // projections
    gemm_f32_kernel<<<dim3(4, 150), blk, 0, stream>>>(x,      256, nullptr, 0, 0, Wq, R0, MROWS, 256, 256, 0);
    gemm_f32_kernel<<<dim3(4, 150), blk, 0, stream>>>(source, 256, nullptr, 0, 0, Wk, R1, MROWS, 256, 256, 0);
    gemm_f32_kernel<<<dim3(4, 150), blk, 0, stream>>>(source, 256, nullptr, 0, 0, Wv, R2, MROWS, 256, 256, 0);

    // gathered attention -> msg (R3)
    attn_kernel<<<dim3(MROWS), blk, 0, stream>>>(R0, R1, R2, eidx, R3);

    // msg @ Wm -> R0
    gemm_f32_kernel<<<dim3(4, 150), blk, 0, stream>>>(R3, 256, nullptr, 0, 0, Wm, R0, MROWS, 256, 256, 0);

    // LN1(R0) -> R3
    ln_kernel<<<dim3(MROWS), blk, 0, stream>>>(R0, g1, b1, nullptr, R3);

    // concat(x, msgln) @ W1, relu -> R1 (9600x512, spans R1..R2)
    gemm_f32_kernel<<<dim3(8, 150), blk, 0, stream>>>(x, 256, R3, 256, 256, W1, R1, MROWS, 512, 512, 1);

    // h1 @ W2 -> R0
    gemm_f32_kernel<<<dim3(4, 150), blk, 0, stream>>>(R1, 512, nullptr, 0, 0, W2, R0, MROWS, 256, 512, 0);

    // out = x + LN2(R0)
    ln_kernel<<<dim3(MROWS), blk, 0, stream>>>(R0, g2, b2, x, out);
}

// Round 2
// 187.701 us; speedup vs baseline: 1.9886x; 1.9886x over previous
//
#include <hip/hip_runtime.h>
#include <hip/hip_bf16.h>

#define D_MODEL 256
#define LQ 4800
#define NB 2
#define MROWS (NB * LQ)       // 9600
#define LN_EPS 1e-5f

typedef unsigned int u32;
typedef unsigned short u16;
typedef __attribute__((ext_vector_type(8))) short bf16x8;
typedef __attribute__((ext_vector_type(4))) float f32x4;

__device__ __forceinline__ float bf2f(u32 bits16) {
    return __uint_as_float(bits16 << 16);
}
__device__ __forceinline__ u16 f2bf(float f) {
    __hip_bfloat16 h = __float2bfloat16(f);
    return *reinterpret_cast<u16*>(&h);
}

// ---------------------------------------------------------------------------
// fp32 -> bf16 cast, 4 elems/thread. n divisible by 4.
// ---------------------------------------------------------------------------
__global__ __launch_bounds__(256) void cvt_bf16_kernel(
    const float* __restrict__ in, u16* __restrict__ out, int n)
{
    int i = (blockIdx.x * 256 + threadIdx.x) * 4;
    if (i >= n) return;
    float4 v = *reinterpret_cast<const float4*>(in + i);
    ushort4 o;
    o.x = f2bf(v.x); o.y = f2bf(v.y); o.z = f2bf(v.z); o.w = f2bf(v.w);
    *reinterpret_cast<ushort4*>(out + i) = o;
}

// ---------------------------------------------------------------------------
// W[K][N] fp32 -> Wt[N][K] bf16 (transpose + cast). grid (N/16, K/16), 256 thr.
// ---------------------------------------------------------------------------
__global__ __launch_bounds__(256) void transpose_w_kernel(
    const float* __restrict__ W, u16* __restrict__ Wt, int K, int N)
{
    __shared__ float tile[16][17];
    int n0 = blockIdx.x * 16, k0 = blockIdx.y * 16;
    int tx = threadIdx.x & 15, ty = threadIdx.x >> 4;
    tile[ty][tx] = W[(size_t)(k0 + ty) * N + n0 + tx];
    __syncthreads();
    Wt[(size_t)(n0 + ty) * K + k0 + tx] = f2bf(tile[tx][ty]);
}

// ---------------------------------------------------------------------------
// bf16 MFMA GEMM: C[M,N] = act(A[M,K] @ Bt[N,K]^T)
// A = virtual concat of A0 (k < splitK) and A1 (k >= splitK) when splitK>0.
// 128x128 tile, BK=32, 256 threads (4 waves, each 64x64 = 4x4 frags of 16x16x32).
// global_load_lds staging with read-side XOR swizzle (chunk ^ (row&3)).
// flags: 1 = relu, 2 = bf16 output (else fp32).
// ---------------------------------------------------------------------------
__global__ __launch_bounds__(256) void gemm_mfma_kernel(
    const u16* __restrict__ A0, int lda0,
    const u16* __restrict__ A1, int lda1, int splitK,
    const u16* __restrict__ Bt, int ldb,
    void* __restrict__ Cout,
    int M, int N, int K, int flags)
{
    __shared__ __align__(16) u16 As[128 * 32];
    __shared__ __align__(16) u16 Bs[128 * 32];

    const int t  = threadIdx.x;
    const int l  = t & 63;
    const int w  = t >> 6;           // wave 0..3
    const int m0 = blockIdx.y * 128;
    const int n0 = blockIdx.x * 128;
    const int wr = w >> 1, wc = w & 1;

    const int srow = l >> 2;                 // row within 16-row stage group
    const int sch  = (l & 3) ^ (srow & 3);   // pre-swizzled source chunk

    f32x4 acc[4][4];
#pragma unroll
    for (int i = 0; i < 4; ++i)
#pragma unroll
        for (int j = 0; j < 4; ++j) acc[i][j] = (f32x4){0.f, 0.f, 0.f, 0.f};

    for (int k0 = 0; k0 < K; k0 += 32) {
        const u16* Ap; int kk, lda;
        if (splitK && k0 >= splitK) { Ap = A1; kk = k0 - splitK; lda = lda1; }
        else                        { Ap = A0; kk = k0;          lda = lda0; }

        // stage A and B tiles: each wave stages 2 groups of 16 rows for each
#pragma unroll
        for (int g = 0; g < 2; ++g) {
            int grp = w * 2 + g;
            int row = grp * 16 + srow;
            const u16* asrc = Ap + (size_t)(m0 + row) * lda + kk + sch * 8;
            u32* adst = (u32*)(As + grp * 512);   // wave-uniform
            __builtin_amdgcn_global_load_lds(
                (const __attribute__((address_space(1))) u32*)asrc,
                (__attribute__((address_space(3))) u32*)adst, 16, 0, 0);
            const u16* bsrc = Bt + (size_t)(n0 + row) * ldb + k0 + sch * 8;
            u32* bdst = (u32*)(Bs + grp * 512);
            __builtin_amdgcn_global_load_lds(
                (const __attribute__((address_space(1))) u32*)bsrc,
                (__attribute__((address_space(3))) u32*)bdst, 16, 0, 0);
        }
        __syncthreads();

        const int r  = l & 15;
        const int ch = l >> 4;
        bf16x8 af[4], bfr[4];
#pragma unroll
        for (int i = 0; i < 4; ++i) {
            int ar = wr * 64 + i * 16 + r;
            af[i] = *(const bf16x8*)((const char*)As + ar * 64 + ((ch ^ (r & 3)) * 16));
        }
#pragma unroll
        for (int j = 0; j < 4; ++j) {
            int br = wc * 64 + j * 16 + r;
            bfr[j] = *(const bf16x8*)((const char*)Bs + br * 64 + ((ch ^ (r & 3)) * 16));
        }
#pragma unroll
        for (int i = 0; i < 4; ++i)
#pragma unroll
            for (int j = 0; j < 4; ++j)
                acc[i][j] = __builtin_amdgcn_mfma_f32_16x16x32_bf16(af[i], bfr[j], acc[i][j], 0, 0, 0);
        __syncthreads();
    }

    // epilogue: C[row][col], col = lane&15, row = (lane>>4)*4 + reg
    const int r  = l & 15;
    const int q4 = l >> 4;
#pragma unroll
    for (int i = 0; i < 4; ++i)
#pragma unroll
        for (int j = 0; j < 4; ++j) {
            int col = n0 + wc * 64 + j * 16 + r;
#pragma unroll
            for (int reg = 0; reg < 4; ++reg) {
                int row = m0 + wr * 64 + i * 16 + q4 * 4 + reg;
                float vv = acc[i][j][reg];
                if (flags & 1) vv = fmaxf(vv, 0.f);
                if (flags & 2) ((u16*)Cout)[(size_t)row * N + col] = f2bf(vv);
                else           ((float*)Cout)[(size_t)row * N + col] = vv;
            }
        }
}

// ---------------------------------------------------------------------------
// Gathered attention, bf16 K/V. One 256-thread block per query.
// q,k,v: [MROWS,256] bf16 head-major. idx: [MROWS,64]. msg: [MROWS,256] bf16.
// LDS row stride 130 dwords (260 bf16) -> 2-way-max bank conflicts (free).
// ---------------------------------------------------------------------------
__global__ __launch_bounds__(256) void attn_bf16_kernel(
    const u16* __restrict__ q, const u16* __restrict__ k,
    const u16* __restrict__ v, const int* __restrict__ idx,
    u16* __restrict__ msg)
{
    __shared__ float q_s[256];
    __shared__ u32   kv_u[32 * 130];
    __shared__ float sc_s[8 * 64];
    __shared__ int   idx_s[64];

    const int t  = threadIdx.x;
    const int qi = blockIdx.x;
    const int n  = qi / LQ;
    const u16* kb = k + (size_t)n * LQ * 256;
    const u16* vb = v + (size_t)n * LQ * 256;

    q_s[t] = bf2f(q[(size_t)qi * 256 + t]);
    if (t < 64) idx_s[t] = idx[(size_t)qi * 64 + t];
    __syncthreads();

    const int h  = t >> 5;
    const int kl = t & 31;
    const int sr = t >> 3;      // staging row 0..31
    const int sg = t & 7;       // staging 64B segment

    // ---- scores ----
    const float scale = 0.17677669529663687f;
    for (int c = 0; c < 2; ++c) {
        const u16* src = kb + (size_t)idx_s[c * 32 + sr] * 256 + sg * 32;
        uint4 a0 = *reinterpret_cast<const uint4*>(src);
        uint4 a1 = *reinterpret_cast<const uint4*>(src + 8);
        uint4 a2 = *reinterpret_cast<const uint4*>(src + 16);
        uint4 a3 = *reinterpret_cast<const uint4*>(src + 24);
        u32* d = kv_u + sr * 130 + sg * 16;
        ((uint2*)d)[0] = make_uint2(a0.x, a0.y); ((uint2*)d)[1] = make_uint2(a0.z, a0.w);
        ((uint2*)d)[2] = make_uint2(a1.x, a1.y); ((uint2*)d)[3] = make_uint2(a1.z, a1.w);
        ((uint2*)d)[4] = make_uint2(a2.x, a2.y); ((uint2*)d)[5] = make_uint2(a2.z, a2.w);
        ((uint2*)d)[6] = make_uint2(a3.x, a3.y); ((uint2*)d)[7] = make_uint2(a3.z, a3.w);
        __syncthreads();

        float acc = 0.f;
        const uint2* kr = (const uint2*)(kv_u + kl * 130 + h * 16);
        const float* qs = &q_s[h * 32];
#pragma unroll
        for (int p = 0; p < 8; ++p) {
            uint2 wv = kr[p];
            acc += bf2f(wv.x & 0xffff) * qs[p * 4 + 0];
            acc += bf2f(wv.x >> 16)    * qs[p * 4 + 1];
            acc += bf2f(wv.y & 0xffff) * qs[p * 4 + 2];
            acc += bf2f(wv.y >> 16)    * qs[p * 4 + 3];
        }
        sc_s[h * 64 + c * 32 + kl] = acc * scale;
        __syncthreads();
    }

    // ---- softmax over 64 keys per head ----
    {
        float s0 = sc_s[h * 64 + kl];
        float s1 = sc_s[h * 64 + 32 + kl];
        float m = fmaxf(s0, s1);
#pragma unroll
        for (int off = 16; off; off >>= 1) m = fmaxf(m, __shfl_xor(m, off, 32));
        float e0 = expf(s0 - m);
        float e1 = expf(s1 - m);
        float sum = e0 + e1;
#pragma unroll
        for (int off = 16; off; off >>= 1) sum += __shfl_xor(sum, off, 32);
        float inv = 1.f / sum;
        sc_s[h * 64 + kl]      = e0 * inv;
        sc_s[h * 64 + 32 + kl] = e1 * inv;
    }

    // ---- msg = attn @ vg ----
    float macc = 0.f;
    const int d = t & 31;
    for (int c = 0; c < 2; ++c) {
        __syncthreads();   // kv_u reuse + sc_s visibility
        const u16* src = vb + (size_t)idx_s[c * 32 + sr] * 256 + sg * 32;
        uint4 a0 = *reinterpret_cast<const uint4*>(src);
        uint4 a1 = *reinterpret_cast<const uint4*>(src + 8);
        uint4 a2 = *reinterpret_cast<const uint4*>(src + 16);
        uint4 a3 = *reinterpret_cast<const uint4*>(src + 24);
        u32* dp = kv_u + sr * 130 + sg * 16;
        ((uint2*)dp)[0] = make_uint2(a0.x, a0.y); ((uint2*)dp)[1] = make_uint2(a0.z, a0.w);
        ((uint2*)dp)[2] = make_uint2(a1.x, a1.y); ((uint2*)dp)[3] = make_uint2(a1.z, a1.w);
        ((uint2*)dp)[4] = make_uint2(a2.x, a2.y); ((uint2*)dp)[5] = make_uint2(a2.z, a2.w);
        ((uint2*)dp)[6] = make_uint2(a3.x, a3.y); ((uint2*)dp)[7] = make_uint2(a3.z, a3.w);
        __syncthreads();
#pragma unroll
        for (int i = 0; i < 32; ++i) {
            u32 wv = kv_u[i * 130 + h * 16 + (d >> 1)];
            float vv = bf2f((d & 1) ? (wv >> 16) : (wv & 0xffff));
            macc = fmaf(sc_s[h * 64 + c * 32 + i], vv, macc);
        }
    }
    msg[(size_t)qi * 256 + t] = f2bf(macc);
}

// ---------------------------------------------------------------------------
// LayerNorm over last dim (256), fp32 input. One block per row.
// out = xadd (if given) + ln(in)*g+b.  out_bf16: write bf16 else fp32.
// ---------------------------------------------------------------------------
__global__ __launch_bounds__(256) void ln_kernel(
    const float* __restrict__ in, const float* __restrict__ g,
    const float* __restrict__ b, const float* __restrict__ xadd,
    void* __restrict__ out, int out_bf16)
{
    __shared__ float red[8];
    const int t = threadIdx.x;
    const size_t row = blockIdx.x;
    float val = in[row * 256 + t];

    float s = val;
#pragma unroll
    for (int off = 32; off; off >>= 1) s += __shfl_down(s, off, 64);
    if ((t & 63) == 0) red[t >> 6] = s;
    __syncthreads();
    float mu = (red[0] + red[1] + red[2] + red[3]) * 0.00390625f;

    float dv = val - mu;
    float s2 = dv * dv;
#pragma unroll
    for (int off = 32; off; off >>= 1) s2 += __shfl_down(s2, off, 64);
    if ((t & 63) == 0) red[4 + (t >> 6)] = s2;
    __syncthreads();
    float var = (red[4] + red[5] + red[6] + red[7]) * 0.00390625f;
    float rstd = rsqrtf(var + LN_EPS);

    float r = dv * rstd * g[t] + b[t];
    if (xadd) r += xadd[row * 256 + t];
    if (out_bf16) ((u16*)out)[row * 256 + t] = f2bf(r);
    else          ((float*)out)[row * 256 + t] = r;
}

// ---------------------------------------------------------------------------
extern "C" void kernel_launch(void* const* d_in, const int* in_sizes, int n_in,
                              void* d_out, int out_size, void* d_ws, size_t ws_size,
                              hipStream_t stream)
{
    const float* x      = (const float*)d_in[0];
    const float* source = (const float*)d_in[1];
    const int*   eidx   = (const int*)d_in[2];
    const float* Wq     = (const float*)d_in[3];
    const float* Wk     = (const float*)d_in[4];
    const float* Wv     = (const float*)d_in[5];
    const float* Wm     = (const float*)d_in[6];
    const float* W1     = (const float*)d_in[7];
    const float* W2     = (const float*)d_in[8];
    const float* g1     = (const float*)d_in[9];
    const float* b1     = (const float*)d_in[10];
    const float* g2     = (const float*)d_in[11];
    const float* b2     = (const float*)d_in[12];
    float* out = (float*)d_out;

    char* ws = (char*)d_ws;
    const size_t SZB = (size_t)MROWS * 256 * 2;   // 4,915,200 B (bf16 [9600,256])
    u16* xb     = (u16*)(ws);                      // live until W1 gemm
    u16* sb     = (u16*)(ws + SZB);                // dead after V gemm
    u16* qb     = (u16*)(ws + 2 * SZB);            // dead after attn
    u16* kb     = (u16*)(ws + 3 * SZB);            // dead after attn
    u16* vb     = (u16*)(ws + 4 * SZB);            // dead after attn
    u16* msgb   = (u16*)(ws + 5 * SZB);            // dead after Wm gemm
    float* msgW = (float*)(ws + SZB);              // f32, overlays sb+qb (dead)
    u16* msglnb = (u16*)(ws + 3 * SZB);            // overlays kb (dead)
    u16* h1b    = (u16*)(ws + 4 * SZB);            // bf16 [9600,512], overlays vb+msgb
    float* h2   = (float*)(ws + SZB);              // f32, overlays msgW (dead)
    u16* Wqt    = (u16*)(ws + 6 * SZB);
    u16* Wkt    = Wqt + 256 * 256;
    u16* Wvt    = Wkt + 256 * 256;
    u16* Wmt    = Wvt + 256 * 256;
    u16* W1t    = Wmt + 256 * 256;                 // [512][512]
    u16* W2t    = W1t + 512 * 512;                 // [256][512]

    dim3 blk(256);
    const int NEL = MROWS * 256;   // 2,457,600

    // casts + weight transposes
    cvt_bf16_kernel<<<dim3(NEL / 1024), blk, 0, stream>>>(x, xb, NEL);
    cvt_bf16_kernel<<<dim3(NEL / 1024), blk, 0, stream>>>(source, sb, NEL);
    transpose_w_kernel<<<dim3(16, 16), blk, 0, stream>>>(Wq, Wqt, 256, 256);
    transpose_w_kernel<<<dim3(16, 16), blk, 0, stream>>>(Wk, Wkt, 256, 256);
    transpose_w_kernel<<<dim3(16, 16), blk, 0, stream>>>(Wv, Wvt, 256, 256);
    transpose_w_kernel<<<dim3(16, 16), blk, 0, stream>>>(Wm, Wmt, 256, 256);
    transpose_w_kernel<<<dim3(32, 32), blk, 0, stream>>>(W1, W1t, 512, 512);
    transpose_w_kernel<<<dim3(16, 32), blk, 0, stream>>>(W2, W2t, 512, 256);

    // projections (bf16 out)
    gemm_mfma_kernel<<<dim3(2, 75), blk, 0, stream>>>(xb, 256, nullptr, 0, 0, Wqt, 256, qb, MROWS, 256, 256, 2);
    gemm_mfma_kernel<<<dim3(2, 75), blk, 0, stream>>>(sb, 256, nullptr, 0, 0, Wkt, 256, kb, MROWS, 256, 256, 2);
    gemm_mfma_kernel<<<dim3(2, 75), blk, 0, stream>>>(sb, 256, nullptr, 0, 0, Wvt, 256, vb, MROWS, 256, 256, 2);

    // gathered attention -> msg (bf16)
    attn_bf16_kernel<<<dim3(MROWS), blk, 0, stream>>>(qb, kb, vb, eidx, msgb);

    // msg @ Wm -> fp32
    gemm_mfma_kernel<<<dim3(2, 75), blk, 0, stream>>>(msgb, 256, nullptr, 0, 0, Wmt, 256, msgW, MROWS, 256, 256, 0);

    // LN1 -> bf16
    ln_kernel<<<dim3(MROWS), blk, 0, stream>>>(msgW, g1, b1, nullptr, msglnb, 1);

    // concat(x, msgln) @ W1, relu -> bf16 [9600,512]
    gemm_mfma_kernel<<<dim3(4, 75), blk, 0, stream>>>(xb, 256, msglnb, 256, 256, W1t, 512, h1b, MROWS, 512, 512, 1 | 2);

    // h1 @ W2 -> fp32
    gemm_mfma_kernel<<<dim3(2, 75), blk, 0, stream>>>(h1b, 512, nullptr, 0, 0, W2t, 512, h2, MROWS, 256, 512, 0);

    // out = x + LN2(h2)
    ln_kernel<<<dim3(MROWS), blk, 0, stream>>>(h2, g2, b2, x, out, 0);
}